// Round 1
// baseline (458.883 us; speedup 1.0000x reference)
//
#include <hip/hip_runtime.h>

#define INC   256
#define HEADS 4
#define OUTC  64
#define NEG_SLOPE 0.2f

// ---------------- GEMM: h = x @ W  (fp32, 64x64 tile, K-step 32) ----------------
__global__ __launch_bounds__(256) void gemm64(const float* __restrict__ A,  // [M,256]
                                              const float* __restrict__ B,  // [256,256]
                                              float* __restrict__ C,        // [M,256]
                                              int M)
{
    __shared__ __align__(16) float As[32][68];  // [k][row]  (68: pad, keeps 16B align)
    __shared__ __align__(16) float Bs[32][68];  // [k][col]
    const int tid = threadIdx.x;
    const int tx = tid & 15, ty = tid >> 4;
    const int row0 = blockIdx.x * 64;
    const int col0 = blockIdx.y * 64;

    float acc[4][4] = {};

    for (int k0 = 0; k0 < INC; k0 += 32) {
        // A tile: rows row0..+63, k k0..+31, stored transposed As[k][row]
        #pragma unroll
        for (int i = 0; i < 2; ++i) {
            int f  = tid + i * 256;        // 0..511
            int r  = f >> 3;               // 0..63
            int k4 = (f & 7) << 2;         // 0,4,...,28
            int gr = row0 + r;
            float4 v = make_float4(0.f, 0.f, 0.f, 0.f);
            if (gr < M) v = *(const float4*)(A + (size_t)gr * INC + k0 + k4);
            As[k4 + 0][r] = v.x; As[k4 + 1][r] = v.y;
            As[k4 + 2][r] = v.z; As[k4 + 3][r] = v.w;
        }
        // B tile: rows k0..+31, cols col0..+63
        #pragma unroll
        for (int i = 0; i < 2; ++i) {
            int f  = tid + i * 256;
            int r  = f >> 4;               // 0..31
            int c4 = (f & 15) << 2;        // 0..60
            float4 v = *(const float4*)(B + (size_t)(k0 + r) * (HEADS * OUTC) + col0 + c4);
            *(float4*)&Bs[r][c4] = v;
        }
        __syncthreads();
        #pragma unroll
        for (int k = 0; k < 32; ++k) {
            float4 av = *(const float4*)&As[k][ty << 2];
            float4 bv = *(const float4*)&Bs[k][tx << 2];
            float a[4] = {av.x, av.y, av.z, av.w};
            float b[4] = {bv.x, bv.y, bv.z, bv.w};
            #pragma unroll
            for (int r = 0; r < 4; ++r)
                #pragma unroll
                for (int c = 0; c < 4; ++c)
                    acc[r][c] = fmaf(a[r], b[c], acc[r][c]);
        }
        __syncthreads();
    }

    #pragma unroll
    for (int r = 0; r < 4; ++r) {
        int gr = row0 + (ty << 2) + r;
        if (gr < M) {
            float4 v = make_float4(acc[r][0], acc[r][1], acc[r][2], acc[r][3]);
            *(float4*)(C + (size_t)gr * (HEADS * OUTC) + col0 + (tx << 2)) = v;
        }
    }
}

// ---------------- a_src/a_dst: per-node per-head dot with attention vectors ----------------
__global__ __launch_bounds__(256) void att_kernel(const float* __restrict__ h,
                                                  const float* __restrict__ att_src,
                                                  const float* __restrict__ att_dst,
                                                  float* __restrict__ a_src,
                                                  float* __restrict__ a_dst, int n)
{
    int w    = (int)((blockIdx.x * blockDim.x + threadIdx.x) >> 6);
    int lane = threadIdx.x & 63;
    if (w >= n) return;
    const float* hr = h + (size_t)w * (HEADS * OUTC);
    float s[HEADS], d[HEADS];
    #pragma unroll
    for (int hh = 0; hh < HEADS; ++hh) {
        float v = hr[hh * OUTC + lane];
        s[hh] = v * att_src[hh * OUTC + lane];
        d[hh] = v * att_dst[hh * OUTC + lane];
    }
    #pragma unroll
    for (int hh = 0; hh < HEADS; ++hh) {
        #pragma unroll
        for (int off = 32; off > 0; off >>= 1) {
            s[hh] += __shfl_down(s[hh], off, 64);
            d[hh] += __shfl_down(d[hh], off, 64);
        }
    }
    if (lane == 0) {
        #pragma unroll
        for (int hh = 0; hh < HEADS; ++hh) {
            a_src[(size_t)w * HEADS + hh] = s[hh];
            a_dst[(size_t)w * HEADS + hh] = d[hh];
        }
    }
}

// ---------------- CSR build ----------------
__global__ void hist_kernel(const int* __restrict__ dst, int* __restrict__ counts, int E)
{
    int e = blockIdx.x * blockDim.x + threadIdx.x;
    if (e < E) atomicAdd(&counts[dst[e]], 1);
}

// single block, 1024 threads; chunked exclusive scan
__global__ __launch_bounds__(1024) void scan_kernel(const int* __restrict__ counts,
                                                    int* __restrict__ offsets,
                                                    int* __restrict__ cursor, int n)
{
    __shared__ int tsum[1024];
    int tid = threadIdx.x;
    int chunk = (n + 1023) / 1024;
    int beg = tid * chunk;
    int end = beg + chunk; if (end > n) end = n;
    int s = 0;
    for (int i = beg; i < end && i >= 0; ++i) s += counts[i];
    tsum[tid] = s;
    __syncthreads();
    // inclusive Hillis-Steele scan
    for (int off = 1; off < 1024; off <<= 1) {
        int v = (tid >= off) ? tsum[tid - off] : 0;
        __syncthreads();
        tsum[tid] += v;
        __syncthreads();
    }
    int base = (tid == 0) ? 0 : tsum[tid - 1];
    for (int i = beg; i < end && i >= 0; ++i) {
        offsets[i] = base;
        cursor[i]  = base;
        base += counts[i];
    }
    if (tid == 1023) offsets[n] = tsum[1023];
}

__global__ void scatter_kernel(const int* __restrict__ src, const int* __restrict__ dst,
                               int* __restrict__ cursor, int* __restrict__ esrc, int E)
{
    int e = blockIdx.x * blockDim.x + threadIdx.x;
    if (e < E) {
        int d = dst[e];
        int pos = atomicAdd(&cursor[d], 1);
        esrc[pos] = src[e];
    }
}

// ---------------- aggregation: one wave per destination node, online softmax ----------------
__global__ __launch_bounds__(256) void aggregate_kernel(
    const float* __restrict__ h,       // [N,256]
    const float* __restrict__ a_src,   // [N,4]
    const float* __restrict__ a_dst,   // [N,4]
    const int*   __restrict__ offsets, // [N+1]
    const int*   __restrict__ esrc,    // [E]
    const float* __restrict__ bias,    // [64]
    float*       __restrict__ out,     // [N,64]
    int n)
{
    int i    = (int)((blockIdx.x * blockDim.x + threadIdx.x) >> 6);
    int lane = threadIdx.x & 63;
    if (i >= n) return;

    float4 adv = *(const float4*)(a_dst + (size_t)i * HEADS);
    float ad[HEADS] = {adv.x, adv.y, adv.z, adv.w};

    float m[HEADS], l[HEADS], acc[HEADS];

    // self loop first (always present): p = 1, m = e_self, l = 1, acc = h[i]
    {
        float4 asv = *(const float4*)(a_src + (size_t)i * HEADS);
        float as[HEADS] = {asv.x, asv.y, asv.z, asv.w};
        const float* hi = h + (size_t)i * (HEADS * OUTC) + lane;
        #pragma unroll
        for (int hh = 0; hh < HEADS; ++hh) {
            float e = as[hh] + ad[hh];
            e = e > 0.f ? e : NEG_SLOPE * e;
            m[hh]   = e;
            l[hh]   = 1.0f;
            acc[hh] = hi[hh * OUTC];
        }
    }

    int beg = offsets[i], end = offsets[i + 1];
    for (int j = beg; j < end; ++j) {
        int s = esrc[j];
        float4 av = *(const float4*)(a_src + (size_t)s * HEADS);
        float asrc[HEADS] = {av.x, av.y, av.z, av.w};
        const float* hs = h + (size_t)s * (HEADS * OUTC) + lane;
        #pragma unroll
        for (int hh = 0; hh < HEADS; ++hh) {
            float e = asrc[hh] + ad[hh];
            e = e > 0.f ? e : NEG_SLOPE * e;
            float mn = fmaxf(m[hh], e);
            float sc = __expf(m[hh] - mn);
            float p  = __expf(e - mn);
            l[hh]   = l[hh] * sc + p;
            acc[hh] = acc[hh] * sc + p * hs[hh * OUTC];
            m[hh]   = mn;
        }
    }

    float o = 0.f;
    #pragma unroll
    for (int hh = 0; hh < HEADS; ++hh) o += acc[hh] / (l[hh] + 1e-16f);
    out[(size_t)i * OUTC + lane] = 0.25f * o + bias[lane];
}

extern "C" void kernel_launch(void* const* d_in, const int* in_sizes, int n_in,
                              void* d_out, int out_size, void* d_ws, size_t ws_size,
                              hipStream_t stream)
{
    (void)n_in; (void)out_size; (void)ws_size;
    const float* x       = (const float*)d_in[0];
    const int*   edge    = (const int*)d_in[1];
    const float* W       = (const float*)d_in[2];
    const float* att_src = (const float*)d_in[3];
    const float* att_dst = (const float*)d_in[4];
    const float* bias    = (const float*)d_in[5];
    float* out = (float*)d_out;

    const int N = in_sizes[0] / INC;
    const int E = in_sizes[1] / 2;
    const int* srcA = edge;
    const int* dstA = edge + E;

    char* ws = (char*)d_ws;
    float* h      = (float*)ws; ws += (size_t)N * (HEADS * OUTC) * sizeof(float);
    float* a_src  = (float*)ws; ws += (size_t)N * HEADS * sizeof(float);
    float* a_dst  = (float*)ws; ws += (size_t)N * HEADS * sizeof(float);
    int* counts   = (int*)ws;   ws += (size_t)N * sizeof(int);
    int* offsets  = (int*)ws;   ws += (size_t)(N + 1) * sizeof(int) + 12; // keep 16B align
    int* cursor   = (int*)ws;   ws += (size_t)N * sizeof(int);
    int* esrc     = (int*)ws;   ws += (size_t)E * sizeof(int);

    hipMemsetAsync(counts, 0, (size_t)N * sizeof(int), stream);

    dim3 gg((N + 63) / 64, (HEADS * OUTC) / 64);
    gemm64<<<gg, 256, 0, stream>>>(x, W, h, N);

    att_kernel<<<(N + 3) / 4, 256, 0, stream>>>(h, att_src, att_dst, a_src, a_dst, N);

    hist_kernel<<<(E + 255) / 256, 256, 0, stream>>>(dstA, counts, E);
    scan_kernel<<<1, 1024, 0, stream>>>(counts, offsets, cursor, N);
    scatter_kernel<<<(E + 255) / 256, 256, 0, stream>>>(srcA, dstA, cursor, esrc, E);

    aggregate_kernel<<<(N + 3) / 4, 256, 0, stream>>>(h, a_src, a_dst, offsets, esrc, bias, out, N);
}

// Round 2
// 451.400 us; speedup vs baseline: 1.0166x; 1.0166x over previous
//
#include <hip/hip_runtime.h>
#include <hip/hip_bf16.h>

#define INC   256
#define HEADS 4
#define OUTC  64
#define NEG_SLOPE 0.2f

__device__ __forceinline__ float bf2f(unsigned short u) {
    union { unsigned int i; float f; } v; v.i = ((unsigned int)u) << 16; return v.f;
}
__device__ __forceinline__ unsigned short f2bf(float x) {
    __hip_bfloat16 b = __float2bfloat16(x);
    return *reinterpret_cast<unsigned short*>(&b);
}

// ---------------- GEMM: h2 = bf16(x @ W)  (fp32 compute, 64x64 tile, K-step 32) ----------------
__global__ __launch_bounds__(256) void gemm64(const float* __restrict__ A,   // [M,256]
                                              const float* __restrict__ B,   // [256,256]
                                              unsigned short* __restrict__ H2, // [M,256] bf16
                                              int M)
{
    __shared__ __align__(16) float As[32][68];
    __shared__ __align__(16) float Bs[32][68];
    const int tid = threadIdx.x;
    const int tx = tid & 15, ty = tid >> 4;
    const int row0 = blockIdx.x * 64;
    const int col0 = blockIdx.y * 64;

    float acc[4][4] = {};

    for (int k0 = 0; k0 < INC; k0 += 32) {
        #pragma unroll
        for (int i = 0; i < 2; ++i) {
            int f  = tid + i * 256;
            int r  = f >> 3;
            int k4 = (f & 7) << 2;
            int gr = row0 + r;
            float4 v = make_float4(0.f, 0.f, 0.f, 0.f);
            if (gr < M) v = *(const float4*)(A + (size_t)gr * INC + k0 + k4);
            As[k4 + 0][r] = v.x; As[k4 + 1][r] = v.y;
            As[k4 + 2][r] = v.z; As[k4 + 3][r] = v.w;
        }
        #pragma unroll
        for (int i = 0; i < 2; ++i) {
            int f  = tid + i * 256;
            int r  = f >> 4;
            int c4 = (f & 15) << 2;
            float4 v = *(const float4*)(B + (size_t)(k0 + r) * (HEADS * OUTC) + col0 + c4);
            *(float4*)&Bs[r][c4] = v;
        }
        __syncthreads();
        #pragma unroll
        for (int k = 0; k < 32; ++k) {
            float4 av = *(const float4*)&As[k][ty << 2];
            float4 bv = *(const float4*)&Bs[k][tx << 2];
            float a[4] = {av.x, av.y, av.z, av.w};
            float b[4] = {bv.x, bv.y, bv.z, bv.w};
            #pragma unroll
            for (int r = 0; r < 4; ++r)
                #pragma unroll
                for (int c = 0; c < 4; ++c)
                    acc[r][c] = fmaf(a[r], b[c], acc[r][c]);
        }
        __syncthreads();
    }

    #pragma unroll
    for (int r = 0; r < 4; ++r) {
        int gr = row0 + (ty << 2) + r;
        if (gr < M) {
            ushort4 v;
            v.x = f2bf(acc[r][0]); v.y = f2bf(acc[r][1]);
            v.z = f2bf(acc[r][2]); v.w = f2bf(acc[r][3]);
            *(ushort4*)(H2 + (size_t)gr * (HEADS * OUTC) + col0 + (tx << 2)) = v;
        }
    }
}

// ---------------- a_src/a_dst from bf16 h2 ----------------
__global__ __launch_bounds__(256) void att2_kernel(const unsigned short* __restrict__ h2,
                                                   const float* __restrict__ att_src,
                                                   const float* __restrict__ att_dst,
                                                   float* __restrict__ a_src,
                                                   float* __restrict__ a_dst, int n)
{
    int w    = (int)((blockIdx.x * blockDim.x + threadIdx.x) >> 6);
    int lane = threadIdx.x & 63;
    if (w >= n) return;
    const unsigned short* hp = h2 + (size_t)w * (HEADS * OUTC) + lane;
    float s[HEADS], d[HEADS];
    #pragma unroll
    for (int hh = 0; hh < HEADS; ++hh) {
        float v = bf2f(hp[hh * OUTC]);
        s[hh] = v * att_src[hh * OUTC + lane];
        d[hh] = v * att_dst[hh * OUTC + lane];
    }
    #pragma unroll
    for (int hh = 0; hh < HEADS; ++hh) {
        #pragma unroll
        for (int off = 32; off > 0; off >>= 1) {
            s[hh] += __shfl_down(s[hh], off, 64);
            d[hh] += __shfl_down(d[hh], off, 64);
        }
    }
    if (lane == 0) {
        float4 sv = make_float4(s[0], s[1], s[2], s[3]);
        float4 dv = make_float4(d[0], d[1], d[2], d[3]);
        *(float4*)(a_src + (size_t)w * HEADS) = sv;
        *(float4*)(a_dst + (size_t)w * HEADS) = dv;
    }
}

// ---------------- CSR build ----------------
__global__ void hist_kernel(const int* __restrict__ dst, int* __restrict__ counts, int E)
{
    int e = blockIdx.x * blockDim.x + threadIdx.x;
    if (e < E) atomicAdd(&counts[dst[e]], 1);
}

__global__ __launch_bounds__(1024) void scan_kernel(const int* __restrict__ counts,
                                                    int* __restrict__ offsets,
                                                    int* __restrict__ cursor, int n)
{
    __shared__ int tsum[1024];
    int tid = threadIdx.x;
    int chunk = (n + 1023) / 1024;
    int beg = tid * chunk;
    int end = beg + chunk; if (end > n) end = n;
    int s = 0;
    for (int i = beg; i < end; ++i) s += counts[i];
    tsum[tid] = s;
    __syncthreads();
    for (int off = 1; off < 1024; off <<= 1) {
        int v = (tid >= off) ? tsum[tid - off] : 0;
        __syncthreads();
        tsum[tid] += v;
        __syncthreads();
    }
    int base = (tid == 0) ? 0 : tsum[tid - 1];
    for (int i = beg; i < end; ++i) {
        offsets[i] = base;
        cursor[i]  = base;
        base += counts[i];
    }
    if (tid == 1023) offsets[n] = tsum[1023];
}

__global__ void scatter_kernel(const int* __restrict__ src, const int* __restrict__ dst,
                               int* __restrict__ cursor,
                               int* __restrict__ esrc, int* __restrict__ edst, int E)
{
    int e = blockIdx.x * blockDim.x + threadIdx.x;
    if (e < E) {
        int d = dst[e];
        int pos = atomicAdd(&cursor[d], 1);
        esrc[pos] = src[e];
        edst[pos] = d;
    }
}

// ---------------- phase A: per-node softmax max & denom (lane-parallel over edges) ----------------
__global__ __launch_bounds__(256) void ml_kernel(const float* __restrict__ a_src,
                                                 const float* __restrict__ a_dst,
                                                 const int*   __restrict__ offsets,
                                                 const int*   __restrict__ esrc,
                                                 float* __restrict__ mbuf,   // [N,4]
                                                 float* __restrict__ lbuf,   // [N,4] = 1/(l+eps)
                                                 int n)
{
    int i    = (int)((blockIdx.x * blockDim.x + threadIdx.x) >> 6);
    int lane = threadIdx.x & 63;
    if (i >= n) return;

    float4 adv = *(const float4*)(a_dst + (size_t)i * HEADS);
    float ad[HEADS] = {adv.x, adv.y, adv.z, adv.w};

    float m[HEADS], l[HEADS];
    #pragma unroll
    for (int hh = 0; hh < HEADS; ++hh) { m[hh] = -1e30f; l[hh] = 0.f; }

    if (lane == 0) {   // self-loop
        float4 asv = *(const float4*)(a_src + (size_t)i * HEADS);
        float as[HEADS] = {asv.x, asv.y, asv.z, asv.w};
        #pragma unroll
        for (int hh = 0; hh < HEADS; ++hh) {
            float e = as[hh] + ad[hh];
            e = e > 0.f ? e : NEG_SLOPE * e;
            m[hh] = e; l[hh] = 1.f;
        }
    }

    int beg = offsets[i], end = offsets[i + 1];
    for (int j = beg + lane; j < end; j += 64) {
        int s = esrc[j];
        float4 av = *(const float4*)(a_src + (size_t)s * HEADS);
        float as[HEADS] = {av.x, av.y, av.z, av.w};
        #pragma unroll
        for (int hh = 0; hh < HEADS; ++hh) {
            float e = as[hh] + ad[hh];
            e = e > 0.f ? e : NEG_SLOPE * e;
            float mn = fmaxf(m[hh], e);
            l[hh] = l[hh] * __expf(m[hh] - mn) + __expf(e - mn);
            m[hh] = mn;
        }
    }

    // merge (m,l) across 64 lanes
    #pragma unroll
    for (int off = 32; off > 0; off >>= 1) {
        #pragma unroll
        for (int hh = 0; hh < HEADS; ++hh) {
            float m2 = __shfl_xor(m[hh], off, 64);
            float l2 = __shfl_xor(l[hh], off, 64);
            float mn = fmaxf(m[hh], m2);
            l[hh] = l[hh] * __expf(m[hh] - mn) + l2 * __expf(m2 - mn);
            m[hh] = mn;
        }
    }

    if (lane == 0) {
        float4 mv = make_float4(m[0], m[1], m[2], m[3]);
        float4 lv = make_float4(1.f / (l[0] + 1e-16f), 1.f / (l[1] + 1e-16f),
                                1.f / (l[2] + 1e-16f), 1.f / (l[3] + 1e-16f));
        *(float4*)(mbuf + (size_t)i * HEADS) = mv;
        *(float4*)(lbuf + (size_t)i * HEADS) = lv;
    }
}

// ---------------- phase A2: per-edge alpha ----------------
__global__ __launch_bounds__(256) void alpha_kernel(const float* __restrict__ a_src,
                                                    const float* __restrict__ a_dst,
                                                    const float* __restrict__ mbuf,
                                                    const float* __restrict__ lbuf,
                                                    const int* __restrict__ esrc,
                                                    const int* __restrict__ edst,
                                                    float* __restrict__ alpha,  // [E,4]
                                                    int E)
{
    int j = blockIdx.x * blockDim.x + threadIdx.x;
    if (j >= E) return;
    int s = esrc[j], d = edst[j];
    float4 av = *(const float4*)(a_src + (size_t)s * HEADS);
    float4 dv = *(const float4*)(a_dst + (size_t)d * HEADS);
    float4 mv = *(const float4*)(mbuf + (size_t)d * HEADS);
    float4 lv = *(const float4*)(lbuf + (size_t)d * HEADS);
    float4 out;
    {
        float e;
        e = av.x + dv.x; e = e > 0.f ? e : NEG_SLOPE * e; out.x = __expf(e - mv.x) * lv.x;
        e = av.y + dv.y; e = e > 0.f ? e : NEG_SLOPE * e; out.y = __expf(e - mv.y) * lv.y;
        e = av.z + dv.z; e = e > 0.f ? e : NEG_SLOPE * e; out.z = __expf(e - mv.z) * lv.z;
        e = av.w + dv.w; e = e > 0.f ? e : NEG_SLOPE * e; out.w = __expf(e - mv.w) * lv.w;
    }
    *(float4*)(alpha + (size_t)j * HEADS) = out;
}

// ---------------- phase B: weighted aggregation, wave per node, lane = channel ----------------
__global__ __launch_bounds__(256) void agg2_kernel(
    const unsigned short* __restrict__ h2,     // [N,256] bf16
    const float* __restrict__ a_src,
    const float* __restrict__ a_dst,
    const float* __restrict__ mbuf,
    const float* __restrict__ lbuf,
    const int*   __restrict__ offsets,
    const int*   __restrict__ esrc,
    const float* __restrict__ alpha,           // [E,4]
    const float* __restrict__ bias,            // [64]
    float*       __restrict__ out,             // [N,64]
    int n)
{
    int i    = (int)((blockIdx.x * blockDim.x + threadIdx.x) >> 6);
    int lane = threadIdx.x & 63;
    if (i >= n) return;

    float4 mv = *(const float4*)(mbuf + (size_t)i * HEADS);
    float4 lv = *(const float4*)(lbuf + (size_t)i * HEADS);

    float acc0, acc1, acc2, acc3;
    {   // self-loop
        float4 av = *(const float4*)(a_src + (size_t)i * HEADS);
        float4 dv = *(const float4*)(a_dst + (size_t)i * HEADS);
        const unsigned short* hp = h2 + (size_t)i * (HEADS * OUTC) + lane;
        float e, p;
        e = av.x + dv.x; e = e > 0.f ? e : NEG_SLOPE * e; p = __expf(e - mv.x) * lv.x;
        acc0 = p * bf2f(hp[0]);
        e = av.y + dv.y; e = e > 0.f ? e : NEG_SLOPE * e; p = __expf(e - mv.y) * lv.y;
        acc1 = p * bf2f(hp[OUTC]);
        e = av.z + dv.z; e = e > 0.f ? e : NEG_SLOPE * e; p = __expf(e - mv.z) * lv.z;
        acc2 = p * bf2f(hp[2 * OUTC]);
        e = av.w + dv.w; e = e > 0.f ? e : NEG_SLOPE * e; p = __expf(e - mv.w) * lv.w;
        acc3 = p * bf2f(hp[3 * OUTC]);
    }

    int beg = offsets[i], end = offsets[i + 1];
    int s = (beg < end) ? esrc[beg] : 0;
    for (int j = beg; j < end; ++j) {
        int snext = (j + 1 < end) ? esrc[j + 1] : 0;
        float4 al = *(const float4*)(alpha + (size_t)j * HEADS);
        const unsigned short* hp = h2 + (size_t)s * (HEADS * OUTC) + lane;
        acc0 = fmaf(al.x, bf2f(hp[0]),        acc0);
        acc1 = fmaf(al.y, bf2f(hp[OUTC]),     acc1);
        acc2 = fmaf(al.z, bf2f(hp[2 * OUTC]), acc2);
        acc3 = fmaf(al.w, bf2f(hp[3 * OUTC]), acc3);
        s = snext;
    }

    out[(size_t)i * OUTC + lane] = 0.25f * (acc0 + acc1 + acc2 + acc3) + bias[lane];
}

extern "C" void kernel_launch(void* const* d_in, const int* in_sizes, int n_in,
                              void* d_out, int out_size, void* d_ws, size_t ws_size,
                              hipStream_t stream)
{
    (void)n_in; (void)out_size; (void)ws_size;
    const float* x       = (const float*)d_in[0];
    const int*   edge    = (const int*)d_in[1];
    const float* W       = (const float*)d_in[2];
    const float* att_src = (const float*)d_in[3];
    const float* att_dst = (const float*)d_in[4];
    const float* bias    = (const float*)d_in[5];
    float* out = (float*)d_out;

    const int N = in_sizes[0] / INC;
    const int E = in_sizes[1] / 2;
    const int* srcA = edge;
    const int* dstA = edge + E;

    char* ws = (char*)d_ws;
    unsigned short* h2 = (unsigned short*)ws; ws += (size_t)N * (HEADS * OUTC) * sizeof(unsigned short);
    float* a_src  = (float*)ws; ws += (size_t)N * HEADS * sizeof(float);
    float* a_dst  = (float*)ws; ws += (size_t)N * HEADS * sizeof(float);
    float* mbuf   = (float*)ws; ws += (size_t)N * HEADS * sizeof(float);
    float* lbuf   = (float*)ws; ws += (size_t)N * HEADS * sizeof(float);
    float* alpha  = (float*)ws; ws += (size_t)E * HEADS * sizeof(float);
    int* counts   = (int*)ws;   ws += (size_t)N * sizeof(int);
    int* offsets  = (int*)ws;   ws += (size_t)(N + 1) * sizeof(int) + 12;
    int* cursor   = (int*)ws;   ws += (size_t)N * sizeof(int);
    int* esrc     = (int*)ws;   ws += (size_t)E * sizeof(int);
    int* edst     = (int*)ws;   ws += (size_t)E * sizeof(int);

    hipMemsetAsync(counts, 0, (size_t)N * sizeof(int), stream);

    dim3 gg((N + 63) / 64, (HEADS * OUTC) / 64);
    gemm64<<<gg, 256, 0, stream>>>(x, W, h2, N);

    att2_kernel<<<(N + 3) / 4, 256, 0, stream>>>(h2, att_src, att_dst, a_src, a_dst, N);

    hist_kernel<<<(E + 255) / 256, 256, 0, stream>>>(dstA, counts, E);
    scan_kernel<<<1, 1024, 0, stream>>>(counts, offsets, cursor, N);
    scatter_kernel<<<(E + 255) / 256, 256, 0, stream>>>(srcA, dstA, cursor, esrc, edst, E);

    ml_kernel<<<(N + 3) / 4, 256, 0, stream>>>(a_src, a_dst, offsets, esrc, mbuf, lbuf, N);
    alpha_kernel<<<(E + 255) / 256, 256, 0, stream>>>(a_src, a_dst, mbuf, lbuf, esrc, edst, alpha, E);
    agg2_kernel<<<(N + 3) / 4, 256, 0, stream>>>(h2, a_src, a_dst, mbuf, lbuf, offsets, esrc, alpha, bias, out, N);
}

// Round 3
// 304.280 us; speedup vs baseline: 1.5081x; 1.4835x over previous
//
#include <hip/hip_runtime.h>
#include <hip/hip_bf16.h>

#define INC   256
#define HEADS 4
#define OUTC  64
#define NEG_SLOPE 0.2f

typedef __attribute__((ext_vector_type(8))) short  fragA;  // 8 bf16 in 4 VGPRs
typedef __attribute__((ext_vector_type(4))) float  f32x4;

__device__ __forceinline__ float bf2f(unsigned short u) {
    union { unsigned int i; float f; } v; v.i = ((unsigned int)u) << 16; return v.f;
}
__device__ __forceinline__ unsigned short f2bf(float x) {
    __hip_bfloat16 b = __float2bfloat16(x);
    return *reinterpret_cast<unsigned short*>(&b);
}

// ---------------- Wt = bf16(W^T)  [256 n][256 k] ----------------
__global__ __launch_bounds__(256) void wt_kernel(const float* __restrict__ W,
                                                 unsigned short* __restrict__ Wt)
{
    int idx = blockIdx.x * 256 + threadIdx.x;   // 65536
    int k = idx >> 8, n = idx & 255;
    Wt[n * 256 + k] = f2bf(W[k * 256 + n]);
}

// ---------------- GEMM: h2 = bf16(x @ W), MFMA 16x16x32 bf16 ----------------
// 64x64 tile, BK=64, 4 waves (2x2), each wave 32x32 (2x2 frags).
__global__ __launch_bounds__(256) void gemm_mfma(
    const float* __restrict__ A,            // [M,256] f32
    const unsigned short* __restrict__ Wt,  // [256 n][256 k] bf16
    unsigned short* __restrict__ H2,        // [M,256] bf16
    int M)
{
    __shared__ __align__(16) unsigned short As[64 * 64]; // [row][k], XOR-swizzled
    __shared__ __align__(16) unsigned short Bs[64 * 64]; // [n][k],   XOR-swizzled
    const int tid  = threadIdx.x;
    const int lane = tid & 63;
    const int wave = tid >> 6;
    const int wm = wave >> 1, wn = wave & 1;
    const int row0 = blockIdx.x * 64;
    const int col0 = blockIdx.y * 64;
    const int g   = lane >> 4;    // 0..3
    const int r16 = lane & 15;

    f32x4 acc[2][2] = {};

    for (int k0 = 0; k0 < INC; k0 += 64) {
        // stage A tile: 64 rows x 64 k, f32 -> bf16, swizzled
        #pragma unroll
        for (int i = 0; i < 4; ++i) {
            int f  = tid + i * 256;          // float4 index 0..1023
            int r  = f >> 4;                 // row 0..63
            int k4 = (f & 15) << 2;          // 0..60
            int gr = row0 + r;
            float4 v = (gr < M) ? *(const float4*)(A + (size_t)gr * INC + k0 + k4)
                                : make_float4(0.f, 0.f, 0.f, 0.f);
            ushort4 u;
            u.x = f2bf(v.x); u.y = f2bf(v.y); u.z = f2bf(v.z); u.w = f2bf(v.w);
            int byte = (r << 7) + (k4 << 1);
            byte ^= (r & 7) << 4;
            *(ushort4*)((char*)As + byte) = u;
        }
        // stage B tile: 64 n x 64 k bf16 from Wt (already transposed), swizzled
        #pragma unroll
        for (int i = 0; i < 2; ++i) {
            int f  = tid + i * 256;          // ushort8 index 0..511
            int r  = f >> 3;                 // n 0..63
            int k8 = (f & 7) << 3;           // 0..56
            int4 v = *(const int4*)(Wt + (size_t)(col0 + r) * 256 + k0 + k8);
            int byte = (r << 7) + (k8 << 1);
            byte ^= (r & 7) << 4;
            *(int4*)((char*)Bs + byte) = v;
        }
        __syncthreads();

        #pragma unroll
        for (int kk = 0; kk < 64; kk += 32) {
            fragA a[2], b[2];
            #pragma unroll
            for (int m = 0; m < 2; ++m) {
                int row  = wm * 32 + m * 16 + r16;
                int byte = (row << 7) + ((kk + g * 8) << 1);
                byte ^= (row & 7) << 4;
                a[m] = *(const fragA*)((const char*)As + byte);
            }
            #pragma unroll
            for (int nn = 0; nn < 2; ++nn) {
                int col  = wn * 32 + nn * 16 + r16;
                int byte = (col << 7) + ((kk + g * 8) << 1);
                byte ^= (col & 7) << 4;
                b[nn] = *(const fragA*)((const char*)Bs + byte);
            }
            #pragma unroll
            for (int m = 0; m < 2; ++m)
                #pragma unroll
                for (int nn = 0; nn < 2; ++nn)
                    acc[m][nn] = __builtin_amdgcn_mfma_f32_16x16x32_bf16(
                        a[m], b[nn], acc[m][nn], 0, 0, 0);
        }
        __syncthreads();
    }

    // C/D layout: col = lane&15, row = (lane>>4)*4 + reg
    #pragma unroll
    for (int m = 0; m < 2; ++m) {
        #pragma unroll
        for (int nn = 0; nn < 2; ++nn) {
            int gcol = col0 + wn * 32 + nn * 16 + r16;
            #pragma unroll
            for (int r = 0; r < 4; ++r) {
                int grow = row0 + wm * 32 + m * 16 + g * 4 + r;
                if (grow < M)
                    H2[(size_t)grow * (HEADS * OUTC) + gcol] = f2bf(acc[m][nn][r]);
            }
        }
    }
}

// ---------------- a_src/a_dst from bf16 h2 ----------------
__global__ __launch_bounds__(256) void att2_kernel(const unsigned short* __restrict__ h2,
                                                   const float* __restrict__ att_src,
                                                   const float* __restrict__ att_dst,
                                                   float* __restrict__ a_src,
                                                   float* __restrict__ a_dst, int n)
{
    int w    = (int)((blockIdx.x * blockDim.x + threadIdx.x) >> 6);
    int lane = threadIdx.x & 63;
    if (w >= n) return;
    const unsigned short* hp = h2 + (size_t)w * (HEADS * OUTC) + lane;
    float s[HEADS], d[HEADS];
    #pragma unroll
    for (int hh = 0; hh < HEADS; ++hh) {
        float v = bf2f(hp[hh * OUTC]);
        s[hh] = v * att_src[hh * OUTC + lane];
        d[hh] = v * att_dst[hh * OUTC + lane];
    }
    #pragma unroll
    for (int hh = 0; hh < HEADS; ++hh) {
        #pragma unroll
        for (int off = 32; off > 0; off >>= 1) {
            s[hh] += __shfl_down(s[hh], off, 64);
            d[hh] += __shfl_down(d[hh], off, 64);
        }
    }
    if (lane == 0) {
        float4 sv = make_float4(s[0], s[1], s[2], s[3]);
        float4 dv = make_float4(d[0], d[1], d[2], d[3]);
        *(float4*)(a_src + (size_t)w * HEADS) = sv;
        *(float4*)(a_dst + (size_t)w * HEADS) = dv;
    }
}

// ---------------- CSR build ----------------
__global__ void hist_kernel(const int* __restrict__ dst, int* __restrict__ counts, int E)
{
    int e = blockIdx.x * blockDim.x + threadIdx.x;
    if (e < E) atomicAdd(&counts[dst[e]], 1);
}

// two-level scan: per-block exclusive scan + block sums
__global__ __launch_bounds__(256) void scan1_kernel(const int* __restrict__ counts,
                                                    int* __restrict__ local,
                                                    int* __restrict__ bsums, int n)
{
    __shared__ int tmp[256];
    int t = threadIdx.x;
    int i = blockIdx.x * 256 + t;
    int v = (i < n) ? counts[i] : 0;
    tmp[t] = v;
    __syncthreads();
    for (int off = 1; off < 256; off <<= 1) {
        int x = (t >= off) ? tmp[t - off] : 0;
        __syncthreads();
        tmp[t] += x;
        __syncthreads();
    }
    if (i < n) local[i] = tmp[t] - v;           // exclusive within block
    if (t == 255) bsums[blockIdx.x] = tmp[255]; // block total
}

__global__ __launch_bounds__(1024) void scan2_kernel(int* __restrict__ bsums, int nb)
{
    __shared__ int tmp[1024];
    int t = threadIdx.x;
    int v = (t < nb) ? bsums[t] : 0;
    tmp[t] = v;
    __syncthreads();
    for (int off = 1; off < 1024; off <<= 1) {
        int x = (t >= off) ? tmp[t - off] : 0;
        __syncthreads();
        tmp[t] += x;
        __syncthreads();
    }
    if (t < nb) bsums[t] = tmp[t] - v;          // exclusive block bases
}

__global__ __launch_bounds__(256) void scan3_kernel(const int* __restrict__ local,
                                                    const int* __restrict__ bsums,
                                                    int* __restrict__ offsets,
                                                    int* __restrict__ cursor,
                                                    int n, int Etot)
{
    int i = blockIdx.x * 256 + threadIdx.x;
    if (i < n) {
        int o = local[i] + bsums[blockIdx.x];
        offsets[i] = o;
        cursor[i]  = o;
    }
    if (i == 0) offsets[n] = Etot;
}

__global__ void scatter_kernel(const int* __restrict__ src, const int* __restrict__ dst,
                               int* __restrict__ cursor,
                               int* __restrict__ esrc, int* __restrict__ edst, int E)
{
    int e = blockIdx.x * blockDim.x + threadIdx.x;
    if (e < E) {
        int d = dst[e];
        int pos = atomicAdd(&cursor[d], 1);
        esrc[pos] = src[e];
        edst[pos] = d;
    }
}

// ---------------- phase A: per-node softmax max & denom ----------------
__global__ __launch_bounds__(256) void ml_kernel(const float* __restrict__ a_src,
                                                 const float* __restrict__ a_dst,
                                                 const int*   __restrict__ offsets,
                                                 const int*   __restrict__ esrc,
                                                 float* __restrict__ mbuf,
                                                 float* __restrict__ lbuf,
                                                 int n)
{
    int i    = (int)((blockIdx.x * blockDim.x + threadIdx.x) >> 6);
    int lane = threadIdx.x & 63;
    if (i >= n) return;

    float4 adv = *(const float4*)(a_dst + (size_t)i * HEADS);
    float ad[HEADS] = {adv.x, adv.y, adv.z, adv.w};

    float m[HEADS], l[HEADS];
    #pragma unroll
    for (int hh = 0; hh < HEADS; ++hh) { m[hh] = -1e30f; l[hh] = 0.f; }

    if (lane == 0) {   // self-loop
        float4 asv = *(const float4*)(a_src + (size_t)i * HEADS);
        float as[HEADS] = {asv.x, asv.y, asv.z, asv.w};
        #pragma unroll
        for (int hh = 0; hh < HEADS; ++hh) {
            float e = as[hh] + ad[hh];
            e = e > 0.f ? e : NEG_SLOPE * e;
            m[hh] = e; l[hh] = 1.f;
        }
    }

    int beg = offsets[i], end = offsets[i + 1];
    for (int j = beg + lane; j < end; j += 64) {
        int s = esrc[j];
        float4 av = *(const float4*)(a_src + (size_t)s * HEADS);
        float as[HEADS] = {av.x, av.y, av.z, av.w};
        #pragma unroll
        for (int hh = 0; hh < HEADS; ++hh) {
            float e = as[hh] + ad[hh];
            e = e > 0.f ? e : NEG_SLOPE * e;
            float mn = fmaxf(m[hh], e);
            l[hh] = l[hh] * __expf(m[hh] - mn) + __expf(e - mn);
            m[hh] = mn;
        }
    }

    #pragma unroll
    for (int off = 32; off > 0; off >>= 1) {
        #pragma unroll
        for (int hh = 0; hh < HEADS; ++hh) {
            float m2 = __shfl_xor(m[hh], off, 64);
            float l2 = __shfl_xor(l[hh], off, 64);
            float mn = fmaxf(m[hh], m2);
            l[hh] = l[hh] * __expf(m[hh] - mn) + l2 * __expf(m2 - mn);
            m[hh] = mn;
        }
    }

    if (lane == 0) {
        float4 mv = make_float4(m[0], m[1], m[2], m[3]);
        float4 lv = make_float4(1.f / (l[0] + 1e-16f), 1.f / (l[1] + 1e-16f),
                                1.f / (l[2] + 1e-16f), 1.f / (l[3] + 1e-16f));
        *(float4*)(mbuf + (size_t)i * HEADS) = mv;
        *(float4*)(lbuf + (size_t)i * HEADS) = lv;
    }
}

// ---------------- phase A2: per-edge alpha ----------------
__global__ __launch_bounds__(256) void alpha_kernel(const float* __restrict__ a_src,
                                                    const float* __restrict__ a_dst,
                                                    const float* __restrict__ mbuf,
                                                    const float* __restrict__ lbuf,
                                                    const int* __restrict__ esrc,
                                                    const int* __restrict__ edst,
                                                    float* __restrict__ alpha,
                                                    int E)
{
    int j = blockIdx.x * blockDim.x + threadIdx.x;
    if (j >= E) return;
    int s = esrc[j], d = edst[j];
    float4 av = *(const float4*)(a_src + (size_t)s * HEADS);
    float4 dv = *(const float4*)(a_dst + (size_t)d * HEADS);
    float4 mv = *(const float4*)(mbuf + (size_t)d * HEADS);
    float4 lv = *(const float4*)(lbuf + (size_t)d * HEADS);
    float4 out;
    float e;
    e = av.x + dv.x; e = e > 0.f ? e : NEG_SLOPE * e; out.x = __expf(e - mv.x) * lv.x;
    e = av.y + dv.y; e = e > 0.f ? e : NEG_SLOPE * e; out.y = __expf(e - mv.y) * lv.y;
    e = av.z + dv.z; e = e > 0.f ? e : NEG_SLOPE * e; out.z = __expf(e - mv.z) * lv.z;
    e = av.w + dv.w; e = e > 0.f ? e : NEG_SLOPE * e; out.w = __expf(e - mv.w) * lv.w;
    *(float4*)(alpha + (size_t)j * HEADS) = out;
}

// ---------------- phase B: weighted aggregation ----------------
__global__ __launch_bounds__(256) void agg2_kernel(
    const unsigned short* __restrict__ h2,
    const float* __restrict__ a_src,
    const float* __restrict__ a_dst,
    const float* __restrict__ mbuf,
    const float* __restrict__ lbuf,
    const int*   __restrict__ offsets,
    const int*   __restrict__ esrc,
    const float* __restrict__ alpha,
    const float* __restrict__ bias,
    float*       __restrict__ out,
    int n)
{
    int i    = (int)((blockIdx.x * blockDim.x + threadIdx.x) >> 6);
    int lane = threadIdx.x & 63;
    if (i >= n) return;

    float4 mv = *(const float4*)(mbuf + (size_t)i * HEADS);
    float4 lv = *(const float4*)(lbuf + (size_t)i * HEADS);

    float acc0, acc1, acc2, acc3;
    {   // self-loop
        float4 av = *(const float4*)(a_src + (size_t)i * HEADS);
        float4 dv = *(const float4*)(a_dst + (size_t)i * HEADS);
        const unsigned short* hp = h2 + (size_t)i * (HEADS * OUTC) + lane;
        float e, p;
        e = av.x + dv.x; e = e > 0.f ? e : NEG_SLOPE * e; p = __expf(e - mv.x) * lv.x;
        acc0 = p * bf2f(hp[0]);
        e = av.y + dv.y; e = e > 0.f ? e : NEG_SLOPE * e; p = __expf(e - mv.y) * lv.y;
        acc1 = p * bf2f(hp[OUTC]);
        e = av.z + dv.z; e = e > 0.f ? e : NEG_SLOPE * e; p = __expf(e - mv.z) * lv.z;
        acc2 = p * bf2f(hp[2 * OUTC]);
        e = av.w + dv.w; e = e > 0.f ? e : NEG_SLOPE * e; p = __expf(e - mv.w) * lv.w;
        acc3 = p * bf2f(hp[3 * OUTC]);
    }

    int beg = offsets[i], end = offsets[i + 1];
    int s = (beg < end) ? esrc[beg] : 0;
    for (int j = beg; j < end; ++j) {
        int snext = (j + 1 < end) ? esrc[j + 1] : 0;
        float4 al = *(const float4*)(alpha + (size_t)j * HEADS);
        const unsigned short* hp = h2 + (size_t)s * (HEADS * OUTC) + lane;
        acc0 = fmaf(al.x, bf2f(hp[0]),        acc0);
        acc1 = fmaf(al.y, bf2f(hp[OUTC]),     acc1);
        acc2 = fmaf(al.z, bf2f(hp[2 * OUTC]), acc2);
        acc3 = fmaf(al.w, bf2f(hp[3 * OUTC]), acc3);
        s = snext;
    }

    out[(size_t)i * OUTC + lane] = 0.25f * (acc0 + acc1 + acc2 + acc3) + bias[lane];
}

extern "C" void kernel_launch(void* const* d_in, const int* in_sizes, int n_in,
                              void* d_out, int out_size, void* d_ws, size_t ws_size,
                              hipStream_t stream)
{
    (void)n_in; (void)out_size; (void)ws_size;
    const float* x       = (const float*)d_in[0];
    const int*   edge    = (const int*)d_in[1];
    const float* W       = (const float*)d_in[2];
    const float* att_src = (const float*)d_in[3];
    const float* att_dst = (const float*)d_in[4];
    const float* bias    = (const float*)d_in[5];
    float* out = (float*)d_out;

    const int N = in_sizes[0] / INC;
    const int E = in_sizes[1] / 2;
    const int* srcA = edge;
    const int* dstA = edge + E;

    char* ws = (char*)d_ws;
    unsigned short* h2 = (unsigned short*)ws; ws += (size_t)N * (HEADS * OUTC) * sizeof(unsigned short);
    unsigned short* Wt = (unsigned short*)ws; ws += (size_t)256 * 256 * sizeof(unsigned short);
    float* a_src  = (float*)ws; ws += (size_t)N * HEADS * sizeof(float);
    float* a_dst  = (float*)ws; ws += (size_t)N * HEADS * sizeof(float);
    float* mbuf   = (float*)ws; ws += (size_t)N * HEADS * sizeof(float);
    float* lbuf   = (float*)ws; ws += (size_t)N * HEADS * sizeof(float);
    float* alpha  = (float*)ws; ws += (size_t)E * HEADS * sizeof(float);
    int* counts   = (int*)ws;   ws += (size_t)N * sizeof(int);
    int* offsets  = (int*)ws;   ws += (size_t)(N + 1) * sizeof(int) + 12;
    int* cursor   = (int*)ws;   ws += (size_t)N * sizeof(int);
    int* local    = (int*)ws;   ws += (size_t)N * sizeof(int);
    int* bsums    = (int*)ws;   ws += (size_t)1024 * sizeof(int);
    int* esrc     = (int*)ws;   ws += (size_t)E * sizeof(int);
    int* edst     = (int*)ws;   ws += (size_t)E * sizeof(int);

    const int nb = (N + 255) / 256;

    hipMemsetAsync(counts, 0, (size_t)N * sizeof(int), stream);

    wt_kernel<<<256, 256, 0, stream>>>(W, Wt);

    dim3 gg((N + 63) / 64, (HEADS * OUTC) / 64);
    gemm_mfma<<<gg, 256, 0, stream>>>(x, Wt, h2, N);

    att2_kernel<<<(N + 3) / 4, 256, 0, stream>>>(h2, att_src, att_dst, a_src, a_dst, N);

    hist_kernel<<<(E + 255) / 256, 256, 0, stream>>>(dstA, counts, E);
    scan1_kernel<<<nb, 256, 0, stream>>>(counts, local, bsums, N);
    scan2_kernel<<<1, 1024, 0, stream>>>(bsums, nb);
    scan3_kernel<<<nb, 256, 0, stream>>>(local, bsums, offsets, cursor, N, E);
    scatter_kernel<<<(E + 255) / 256, 256, 0, stream>>>(srcA, dstA, cursor, esrc, edst, E);

    ml_kernel<<<(N + 3) / 4, 256, 0, stream>>>(a_src, a_dst, offsets, esrc, mbuf, lbuf, N);
    alpha_kernel<<<(E + 255) / 256, 256, 0, stream>>>(a_src, a_dst, mbuf, lbuf, esrc, edst, alpha, E);
    agg2_kernel<<<(N + 3) / 4, 256, 0, stream>>>(h2, a_src, a_dst, mbuf, lbuf, offsets, esrc, alpha, bias, out, N);
}

// Round 4
// 238.390 us; speedup vs baseline: 1.9249x; 1.2764x over previous
//
#include <hip/hip_runtime.h>
#include <hip/hip_bf16.h>

#define INC   256
#define HEADS 4
#define OUTC  64
#define NEG_SLOPE 0.2f

typedef __attribute__((ext_vector_type(8))) short  fragA;  // 8 bf16 in 4 VGPRs
typedef __attribute__((ext_vector_type(4))) float  f32x4;

__device__ __forceinline__ float bf2f(unsigned short u) {
    union { unsigned int i; float f; } v; v.i = ((unsigned int)u) << 16; return v.f;
}
__device__ __forceinline__ unsigned short f2bf(float x) {
    __hip_bfloat16 b = __float2bfloat16(x);
    return *reinterpret_cast<unsigned short*>(&b);
}

// ---------------- Wt = bf16(W^T)  [256 n][256 k] ----------------
__global__ __launch_bounds__(256) void wt_kernel(const float* __restrict__ W,
                                                 unsigned short* __restrict__ Wt)
{
    int idx = blockIdx.x * 256 + threadIdx.x;   // 65536
    int k = idx >> 8, n = idx & 255;
    Wt[n * 256 + k] = f2bf(W[k * 256 + n]);
}

// ---------------- GEMM: h2 = bf16(x @ W), MFMA 16x16x32 bf16 ----------------
__global__ __launch_bounds__(256) void gemm_mfma(
    const float* __restrict__ A,            // [M,256] f32
    const unsigned short* __restrict__ Wt,  // [256 n][256 k] bf16
    unsigned short* __restrict__ H2,        // [M,256] bf16
    int M)
{
    __shared__ __align__(16) unsigned short As[64 * 64];
    __shared__ __align__(16) unsigned short Bs[64 * 64];
    const int tid  = threadIdx.x;
    const int lane = tid & 63;
    const int wave = tid >> 6;
    const int wm = wave >> 1, wn = wave & 1;
    const int row0 = blockIdx.x * 64;
    const int col0 = blockIdx.y * 64;
    const int g   = lane >> 4;
    const int r16 = lane & 15;

    f32x4 acc[2][2] = {};

    for (int k0 = 0; k0 < INC; k0 += 64) {
        #pragma unroll
        for (int i = 0; i < 4; ++i) {
            int f  = tid + i * 256;
            int r  = f >> 4;
            int k4 = (f & 15) << 2;
            int gr = row0 + r;
            float4 v = (gr < M) ? *(const float4*)(A + (size_t)gr * INC + k0 + k4)
                                : make_float4(0.f, 0.f, 0.f, 0.f);
            ushort4 u;
            u.x = f2bf(v.x); u.y = f2bf(v.y); u.z = f2bf(v.z); u.w = f2bf(v.w);
            int byte = (r << 7) + (k4 << 1);
            byte ^= (r & 7) << 4;
            *(ushort4*)((char*)As + byte) = u;
        }
        #pragma unroll
        for (int i = 0; i < 2; ++i) {
            int f  = tid + i * 256;
            int r  = f >> 3;
            int k8 = (f & 7) << 3;
            int4 v = *(const int4*)(Wt + (size_t)(col0 + r) * 256 + k0 + k8);
            int byte = (r << 7) + (k8 << 1);
            byte ^= (r & 7) << 4;
            *(int4*)((char*)Bs + byte) = v;
        }
        __syncthreads();

        #pragma unroll
        for (int kk = 0; kk < 64; kk += 32) {
            fragA a[2], b[2];
            #pragma unroll
            for (int m = 0; m < 2; ++m) {
                int row  = wm * 32 + m * 16 + r16;
                int byte = (row << 7) + ((kk + g * 8) << 1);
                byte ^= (row & 7) << 4;
                a[m] = *(const fragA*)((const char*)As + byte);
            }
            #pragma unroll
            for (int nn = 0; nn < 2; ++nn) {
                int col  = wn * 32 + nn * 16 + r16;
                int byte = (col << 7) + ((kk + g * 8) << 1);
                byte ^= (col & 7) << 4;
                b[nn] = *(const fragA*)((const char*)Bs + byte);
            }
            #pragma unroll
            for (int m = 0; m < 2; ++m)
                #pragma unroll
                for (int nn = 0; nn < 2; ++nn)
                    acc[m][nn] = __builtin_amdgcn_mfma_f32_16x16x32_bf16(
                        a[m], b[nn], acc[m][nn], 0, 0, 0);
        }
        __syncthreads();
    }

    #pragma unroll
    for (int m = 0; m < 2; ++m) {
        #pragma unroll
        for (int nn = 0; nn < 2; ++nn) {
            int gcol = col0 + wn * 32 + nn * 16 + r16;
            #pragma unroll
            for (int r = 0; r < 4; ++r) {
                int grow = row0 + wm * 32 + m * 16 + g * 4 + r;
                if (grow < M)
                    H2[(size_t)grow * (HEADS * OUTC) + gcol] = f2bf(acc[m][nn][r]);
            }
        }
    }
}

// ---------------- a_src/a_dst from bf16 h2 ----------------
__global__ __launch_bounds__(256) void att2_kernel(const unsigned short* __restrict__ h2,
                                                   const float* __restrict__ att_src,
                                                   const float* __restrict__ att_dst,
                                                   float* __restrict__ a_src,
                                                   float* __restrict__ a_dst, int n)
{
    int w    = (int)((blockIdx.x * blockDim.x + threadIdx.x) >> 6);
    int lane = threadIdx.x & 63;
    if (w >= n) return;
    const unsigned short* hp = h2 + (size_t)w * (HEADS * OUTC) + lane;
    float s[HEADS], d[HEADS];
    #pragma unroll
    for (int hh = 0; hh < HEADS; ++hh) {
        float v = bf2f(hp[hh * OUTC]);
        s[hh] = v * att_src[hh * OUTC + lane];
        d[hh] = v * att_dst[hh * OUTC + lane];
    }
    #pragma unroll
    for (int hh = 0; hh < HEADS; ++hh) {
        #pragma unroll
        for (int off = 32; off > 0; off >>= 1) {
            s[hh] += __shfl_down(s[hh], off, 64);
            d[hh] += __shfl_down(d[hh], off, 64);
        }
    }
    if (lane == 0) {
        float4 sv = make_float4(s[0], s[1], s[2], s[3]);
        float4 dv = make_float4(d[0], d[1], d[2], d[3]);
        *(float4*)(a_src + (size_t)w * HEADS) = sv;
        *(float4*)(a_dst + (size_t)w * HEADS) = dv;
    }
}

// ---------------- CSR build ----------------
__global__ void hist_kernel(const int* __restrict__ dst, int* __restrict__ counts, int E)
{
    int e = blockIdx.x * blockDim.x + threadIdx.x;
    if (e < E) atomicAdd(&counts[dst[e]], 1);
}

__global__ __launch_bounds__(256) void scan1_kernel(const int* __restrict__ counts,
                                                    int* __restrict__ local,
                                                    int* __restrict__ bsums, int n)
{
    __shared__ int tmp[256];
    int t = threadIdx.x;
    int i = blockIdx.x * 256 + t;
    int v = (i < n) ? counts[i] : 0;
    tmp[t] = v;
    __syncthreads();
    for (int off = 1; off < 256; off <<= 1) {
        int x = (t >= off) ? tmp[t - off] : 0;
        __syncthreads();
        tmp[t] += x;
        __syncthreads();
    }
    if (i < n) local[i] = tmp[t] - v;
    if (t == 255) bsums[blockIdx.x] = tmp[255];
}

__global__ __launch_bounds__(1024) void scan2_kernel(int* __restrict__ bsums, int nb)
{
    __shared__ int tmp[1024];
    int t = threadIdx.x;
    int v = (t < nb) ? bsums[t] : 0;
    tmp[t] = v;
    __syncthreads();
    for (int off = 1; off < 1024; off <<= 1) {
        int x = (t >= off) ? tmp[t - off] : 0;
        __syncthreads();
        tmp[t] += x;
        __syncthreads();
    }
    if (t < nb) bsums[t] = tmp[t] - v;
}

__global__ __launch_bounds__(256) void scan3_kernel(const int* __restrict__ local,
                                                    const int* __restrict__ bsums,
                                                    int* __restrict__ offsets,
                                                    int* __restrict__ cursor,
                                                    int n, int Etot)
{
    int i = blockIdx.x * 256 + threadIdx.x;
    if (i < n) {
        int o = local[i] + bsums[blockIdx.x];
        offsets[i] = o;
        cursor[i]  = o;
    }
    if (i == 0) offsets[n] = Etot;
}

__global__ void scatter_kernel(const int* __restrict__ src, const int* __restrict__ dst,
                               int* __restrict__ cursor,
                               int* __restrict__ esrc, int E)
{
    int e = blockIdx.x * blockDim.x + threadIdx.x;
    if (e < E) {
        int d = dst[e];
        int pos = atomicAdd(&cursor[d], 1);
        esrc[pos] = src[e];
    }
}

// ---------------- fused softmax + aggregation: one pass, no max shift ----------------
// wave per node; lane = head*16 + chgroup; each lane owns 4 channels of 1 head.
__global__ __launch_bounds__(256) void fused_agg_kernel(
    const unsigned short* __restrict__ h2,      // [N,256] bf16
    const float* __restrict__ a_src,            // [N,4]
    const float* __restrict__ a_dst,            // [N,4]
    const int*   __restrict__ offsets,          // [N+1]
    const int*   __restrict__ esrc,             // [E]
    const float* __restrict__ bias,             // [64]
    float*       __restrict__ out,              // [N,64]
    int n)
{
    int i    = (int)((blockIdx.x * blockDim.x + threadIdx.x) >> 6);
    int lane = threadIdx.x & 63;
    if (i >= n) return;
    const int h  = lane >> 4;   // head 0..3
    const int cg = lane & 15;   // channel group (4 ch)

    const float ad = a_dst[(size_t)i * HEADS + h];

    float acc0 = 0.f, acc1 = 0.f, acc2 = 0.f, acc3 = 0.f, l = 0.f;

    // self-loop (ushort offset = h*64 + cg*4 == lane*4)
    {
        float as = a_src[(size_t)i * HEADS + h];
        ushort4 v = *(const ushort4*)(h2 + (size_t)i * 256 + lane * 4);
        float e = as + ad; e = e > 0.f ? e : NEG_SLOPE * e;
        float p = __expf(e);
        l += p;
        acc0 = fmaf(p, bf2f(v.x), acc0);
        acc1 = fmaf(p, bf2f(v.y), acc1);
        acc2 = fmaf(p, bf2f(v.z), acc2);
        acc3 = fmaf(p, bf2f(v.w), acc3);
    }

    int beg = offsets[i], end = offsets[i + 1];
    int j = beg;
    for (; j + 1 < end; j += 2) {
        int s0 = esrc[j], s1 = esrc[j + 1];
        float as0 = a_src[(size_t)s0 * HEADS + h];
        float as1 = a_src[(size_t)s1 * HEADS + h];
        ushort4 v0 = *(const ushort4*)(h2 + (size_t)s0 * 256 + lane * 4);
        ushort4 v1 = *(const ushort4*)(h2 + (size_t)s1 * 256 + lane * 4);
        float e0 = as0 + ad; e0 = e0 > 0.f ? e0 : NEG_SLOPE * e0;
        float e1 = as1 + ad; e1 = e1 > 0.f ? e1 : NEG_SLOPE * e1;
        float p0 = __expf(e0);
        float p1 = __expf(e1);
        l += p0 + p1;
        acc0 = fmaf(p0, bf2f(v0.x), acc0);
        acc1 = fmaf(p0, bf2f(v0.y), acc1);
        acc2 = fmaf(p0, bf2f(v0.z), acc2);
        acc3 = fmaf(p0, bf2f(v0.w), acc3);
        acc0 = fmaf(p1, bf2f(v1.x), acc0);
        acc1 = fmaf(p1, bf2f(v1.y), acc1);
        acc2 = fmaf(p1, bf2f(v1.z), acc2);
        acc3 = fmaf(p1, bf2f(v1.w), acc3);
    }
    if (j < end) {
        int s0 = esrc[j];
        float as0 = a_src[(size_t)s0 * HEADS + h];
        ushort4 v0 = *(const ushort4*)(h2 + (size_t)s0 * 256 + lane * 4);
        float e0 = as0 + ad; e0 = e0 > 0.f ? e0 : NEG_SLOPE * e0;
        float p0 = __expf(e0);
        l += p0;
        acc0 = fmaf(p0, bf2f(v0.x), acc0);
        acc1 = fmaf(p0, bf2f(v0.y), acc1);
        acc2 = fmaf(p0, bf2f(v0.z), acc2);
        acc3 = fmaf(p0, bf2f(v0.w), acc3);
    }

    float inv = 1.f / (l + 1e-16f);
    float r0 = acc0 * inv, r1 = acc1 * inv, r2 = acc2 * inv, r3 = acc3 * inv;

    // sum the 4 heads: lanes {cg, 16+cg, 32+cg, 48+cg}
    r0 += __shfl_xor(r0, 16, 64); r0 += __shfl_xor(r0, 32, 64);
    r1 += __shfl_xor(r1, 16, 64); r1 += __shfl_xor(r1, 32, 64);
    r2 += __shfl_xor(r2, 16, 64); r2 += __shfl_xor(r2, 32, 64);
    r3 += __shfl_xor(r3, 16, 64); r3 += __shfl_xor(r3, 32, 64);

    if (lane < 16) {
        float4 b4 = *(const float4*)(bias + cg * 4);
        float4 o;
        o.x = 0.25f * r0 + b4.x;
        o.y = 0.25f * r1 + b4.y;
        o.z = 0.25f * r2 + b4.z;
        o.w = 0.25f * r3 + b4.w;
        *(float4*)(out + (size_t)i * OUTC + cg * 4) = o;
    }
}

extern "C" void kernel_launch(void* const* d_in, const int* in_sizes, int n_in,
                              void* d_out, int out_size, void* d_ws, size_t ws_size,
                              hipStream_t stream)
{
    (void)n_in; (void)out_size; (void)ws_size;
    const float* x       = (const float*)d_in[0];
    const int*   edge    = (const int*)d_in[1];
    const float* W       = (const float*)d_in[2];
    const float* att_src = (const float*)d_in[3];
    const float* att_dst = (const float*)d_in[4];
    const float* bias    = (const float*)d_in[5];
    float* out = (float*)d_out;

    const int N = in_sizes[0] / INC;
    const int E = in_sizes[1] / 2;
    const int* srcA = edge;
    const int* dstA = edge + E;

    char* ws = (char*)d_ws;
    unsigned short* h2 = (unsigned short*)ws; ws += (size_t)N * (HEADS * OUTC) * sizeof(unsigned short);
    unsigned short* Wt = (unsigned short*)ws; ws += (size_t)256 * 256 * sizeof(unsigned short);
    float* a_src  = (float*)ws; ws += (size_t)N * HEADS * sizeof(float);
    float* a_dst  = (float*)ws; ws += (size_t)N * HEADS * sizeof(float);
    int* counts   = (int*)ws;   ws += (size_t)N * sizeof(int);
    int* offsets  = (int*)ws;   ws += (size_t)(N + 1) * sizeof(int) + 12;
    int* cursor   = (int*)ws;   ws += (size_t)N * sizeof(int);
    int* local    = (int*)ws;   ws += (size_t)N * sizeof(int);
    int* bsums    = (int*)ws;   ws += (size_t)1024 * sizeof(int);
    int* esrc     = (int*)ws;   ws += (size_t)E * sizeof(int);

    const int nb = (N + 255) / 256;

    hipMemsetAsync(counts, 0, (size_t)N * sizeof(int), stream);

    wt_kernel<<<256, 256, 0, stream>>>(W, Wt);

    dim3 gg((N + 63) / 64, (HEADS * OUTC) / 64);
    gemm_mfma<<<gg, 256, 0, stream>>>(x, Wt, h2, N);

    att2_kernel<<<(N + 3) / 4, 256, 0, stream>>>(h2, att_src, att_dst, a_src, a_dst, N);

    hist_kernel<<<(E + 255) / 256, 256, 0, stream>>>(dstA, counts, E);
    scan1_kernel<<<nb, 256, 0, stream>>>(counts, local, bsums, N);
    scan2_kernel<<<1, 1024, 0, stream>>>(bsums, nb);
    scan3_kernel<<<nb, 256, 0, stream>>>(local, bsums, offsets, cursor, N, E);
    scatter_kernel<<<(E + 255) / 256, 256, 0, stream>>>(srcA, dstA, cursor, esrc, E);

    fused_agg_kernel<<<(N + 3) / 4, 256, 0, stream>>>(h2, a_src, a_dst, offsets, esrc, bias, out, N);
}

// Round 5
// 208.590 us; speedup vs baseline: 2.1999x; 1.1429x over previous
//
#include <hip/hip_runtime.h>
#include <hip/hip_bf16.h>

#define INC   256
#define HEADS 4
#define OUTC  64
#define NEG_SLOPE 0.2f

typedef __attribute__((ext_vector_type(8))) short  fragA;  // 8 bf16 in 4 VGPRs
typedef __attribute__((ext_vector_type(4))) float  f32x4;

__device__ __forceinline__ float bf2f(unsigned short u) {
    union { unsigned int i; float f; } v; v.i = ((unsigned int)u) << 16; return v.f;
}
__device__ __forceinline__ unsigned short f2bf(float x) {
    __hip_bfloat16 b = __float2bfloat16(x);
    return *reinterpret_cast<unsigned short*>(&b);
}

// ---------------- Wt = bf16(W^T) [256 n][256 k]; also zero counts ----------------
__global__ __launch_bounds__(256) void wt_zero_kernel(const float* __restrict__ W,
                                                      unsigned short* __restrict__ Wt,
                                                      int* __restrict__ counts, int n)
{
    int idx = blockIdx.x * 256 + threadIdx.x;   // 0..65535
    int k = idx >> 8, c = idx & 255;
    Wt[c * 256 + k] = f2bf(W[k * 256 + c]);
    if (idx < n) counts[idx] = 0;
}

// ---------------- GEMM: h2 = bf16(x @ W), MFMA 16x16x32 bf16 ----------------
// grid (M/64, 1): each block 64 rows x 256 cols; 4 waves, each a 64-col slice (4x4 frags).
__global__ __launch_bounds__(256) void gemm_mfma(
    const float* __restrict__ A,            // [M,256] f32
    const unsigned short* __restrict__ Wt,  // [256 n][256 k] bf16
    unsigned short* __restrict__ H2,        // [M,256] bf16
    int M)
{
    __shared__ __align__(16) unsigned short As[64 * 64];    // 8 KB, swizzled
    __shared__ __align__(16) unsigned short Bs[256 * 64];   // 32 KB, swizzled
    const int tid  = threadIdx.x;
    const int lane = tid & 63;
    const int wave = tid >> 6;          // 0..3 -> col slice
    const int row0 = blockIdx.x * 64;
    const int g   = lane >> 4;
    const int r16 = lane & 15;

    f32x4 acc[4][4] = {};

    for (int k0 = 0; k0 < INC; k0 += 64) {
        // stage A: 64 rows x 64 k, f32 -> bf16
        #pragma unroll
        for (int i = 0; i < 4; ++i) {
            int f  = tid + i * 256;
            int r  = f >> 4;
            int k4 = (f & 15) << 2;
            int gr = row0 + r;
            float4 v = (gr < M) ? *(const float4*)(A + (size_t)gr * INC + k0 + k4)
                                : make_float4(0.f, 0.f, 0.f, 0.f);
            ushort4 u;
            u.x = f2bf(v.x); u.y = f2bf(v.y); u.z = f2bf(v.z); u.w = f2bf(v.w);
            int byte = (r << 7) + (k4 << 1);
            byte ^= (r & 7) << 4;
            *(ushort4*)((char*)As + byte) = u;
        }
        // stage B: 256 n x 64 k bf16 from Wt
        #pragma unroll
        for (int i = 0; i < 8; ++i) {
            int f  = tid + i * 256;
            int r  = f >> 3;                 // n 0..255
            int k8 = (f & 7) << 3;           // 0..56
            int4 v = *(const int4*)(Wt + (size_t)r * 256 + k0 + k8);
            int byte = (r << 7) + (k8 << 1);
            byte ^= (r & 7) << 4;
            *(int4*)((char*)Bs + byte) = v;
        }
        __syncthreads();

        #pragma unroll
        for (int kk = 0; kk < 64; kk += 32) {
            fragA a[4], b[4];
            #pragma unroll
            for (int m = 0; m < 4; ++m) {
                int row  = m * 16 + r16;
                int byte = (row << 7) + ((kk + g * 8) << 1);
                byte ^= (row & 7) << 4;
                a[m] = *(const fragA*)((const char*)As + byte);
            }
            #pragma unroll
            for (int nn = 0; nn < 4; ++nn) {
                int col  = wave * 64 + nn * 16 + r16;
                int byte = (col << 7) + ((kk + g * 8) << 1);
                byte ^= (col & 7) << 4;
                b[nn] = *(const fragA*)((const char*)Bs + byte);
            }
            #pragma unroll
            for (int m = 0; m < 4; ++m)
                #pragma unroll
                for (int nn = 0; nn < 4; ++nn)
                    acc[m][nn] = __builtin_amdgcn_mfma_f32_16x16x32_bf16(
                        a[m], b[nn], acc[m][nn], 0, 0, 0);
        }
        __syncthreads();
    }

    // C/D layout: col = lane&15, row = (lane>>4)*4 + reg
    #pragma unroll
    for (int m = 0; m < 4; ++m) {
        #pragma unroll
        for (int nn = 0; nn < 4; ++nn) {
            int gcol = wave * 64 + nn * 16 + r16;
            #pragma unroll
            for (int r = 0; r < 4; ++r) {
                int grow = row0 + m * 16 + g * 4 + r;
                if (grow < M)
                    H2[(size_t)grow * (HEADS * OUTC) + gcol] = f2bf(acc[m][nn][r]);
            }
        }
    }
}

// ---------------- a_src/a_dst from bf16 h2 ----------------
__global__ __launch_bounds__(256) void att2_kernel(const unsigned short* __restrict__ h2,
                                                   const float* __restrict__ att_src,
                                                   const float* __restrict__ att_dst,
                                                   float* __restrict__ a_src,
                                                   float* __restrict__ a_dst, int n)
{
    int w    = (int)((blockIdx.x * blockDim.x + threadIdx.x) >> 6);
    int lane = threadIdx.x & 63;
    if (w >= n) return;
    const unsigned short* hp = h2 + (size_t)w * (HEADS * OUTC) + lane;
    float s[HEADS], d[HEADS];
    #pragma unroll
    for (int hh = 0; hh < HEADS; ++hh) {
        float v = bf2f(hp[hh * OUTC]);
        s[hh] = v * att_src[hh * OUTC + lane];
        d[hh] = v * att_dst[hh * OUTC + lane];
    }
    #pragma unroll
    for (int hh = 0; hh < HEADS; ++hh) {
        #pragma unroll
        for (int off = 32; off > 0; off >>= 1) {
            s[hh] += __shfl_down(s[hh], off, 64);
            d[hh] += __shfl_down(d[hh], off, 64);
        }
    }
    if (lane == 0) {
        float4 sv = make_float4(s[0], s[1], s[2], s[3]);
        float4 dv = make_float4(d[0], d[1], d[2], d[3]);
        *(float4*)(a_src + (size_t)w * HEADS) = sv;
        *(float4*)(a_dst + (size_t)w * HEADS) = dv;
    }
}

// ---------------- CSR build ----------------
__global__ void hist_kernel(const int* __restrict__ dst, int* __restrict__ counts, int E)
{
    int e = blockIdx.x * blockDim.x + threadIdx.x;
    if (e < E) atomicAdd(&counts[dst[e]], 1);
}

__global__ __launch_bounds__(256) void scan1_kernel(const int* __restrict__ counts,
                                                    int* __restrict__ local,
                                                    int* __restrict__ bsums, int n)
{
    __shared__ int tmp[256];
    int t = threadIdx.x;
    int i = blockIdx.x * 256 + t;
    int v = (i < n) ? counts[i] : 0;
    tmp[t] = v;
    __syncthreads();
    for (int off = 1; off < 256; off <<= 1) {
        int x = (t >= off) ? tmp[t - off] : 0;
        __syncthreads();
        tmp[t] += x;
        __syncthreads();
    }
    if (i < n) local[i] = tmp[t] - v;
    if (t == 255) bsums[blockIdx.x] = tmp[255];
}

// each block computes its base by summing preceding block sums (nb ~ 196, trivial)
__global__ __launch_bounds__(256) void scan3b_kernel(const int* __restrict__ local,
                                                     const int* __restrict__ bsums,
                                                     int* __restrict__ offsets,
                                                     int* __restrict__ cursor,
                                                     int n, int Etot)
{
    __shared__ int red[256];
    int t = threadIdx.x;
    int bid = blockIdx.x;
    int s = 0;
    for (int j = t; j < bid; j += 256) s += bsums[j];
    red[t] = s;
    __syncthreads();
    for (int off = 128; off > 0; off >>= 1) {
        if (t < off) red[t] += red[t + off];
        __syncthreads();
    }
    int base = red[0];
    int i = bid * 256 + t;
    if (i < n) {
        int o = local[i] + base;
        offsets[i] = o;
        cursor[i]  = o;
    }
    if (bid == 0 && t == 0) offsets[n] = Etot;
}

__global__ void scatter_kernel(const int* __restrict__ src, const int* __restrict__ dst,
                               int* __restrict__ cursor,
                               int* __restrict__ esrc, int E)
{
    int e = blockIdx.x * blockDim.x + threadIdx.x;
    if (e < E) {
        int d = dst[e];
        int pos = atomicAdd(&cursor[d], 1);
        esrc[pos] = src[e];
    }
}

// ---------------- fused softmax + aggregation: one pass, no max shift ----------------
// wave per node; lane = head*16 + chgroup; each lane owns 4 channels of 1 head.
__global__ __launch_bounds__(256) void fused_agg_kernel(
    const unsigned short* __restrict__ h2,      // [N,256] bf16
    const float* __restrict__ a_src,            // [N,4]
    const float* __restrict__ a_dst,            // [N,4]
    const int*   __restrict__ offsets,          // [N+1]
    const int*   __restrict__ esrc,             // [E]
    const float* __restrict__ bias,             // [64]
    float*       __restrict__ out,              // [N,64]
    int n)
{
    int i    = (int)((blockIdx.x * blockDim.x + threadIdx.x) >> 6);
    int lane = threadIdx.x & 63;
    if (i >= n) return;
    const int h  = lane >> 4;   // head 0..3
    const int cg = lane & 15;   // channel group (4 ch)

    const float ad = a_dst[(size_t)i * HEADS + h];

    float acc0 = 0.f, acc1 = 0.f, acc2 = 0.f, acc3 = 0.f, l = 0.f;

    // self-loop (ushort offset = h*64 + cg*4 == lane*4)
    {
        float as = a_src[(size_t)i * HEADS + h];
        ushort4 v = *(const ushort4*)(h2 + (size_t)i * 256 + lane * 4);
        float e = as + ad; e = e > 0.f ? e : NEG_SLOPE * e;
        float p = __expf(e);
        l += p;
        acc0 = fmaf(p, bf2f(v.x), acc0);
        acc1 = fmaf(p, bf2f(v.y), acc1);
        acc2 = fmaf(p, bf2f(v.z), acc2);
        acc3 = fmaf(p, bf2f(v.w), acc3);
    }

    int beg = offsets[i], end = offsets[i + 1];
    int j = beg;
    for (; j + 3 < end; j += 4) {
        int s0 = esrc[j];
        int s1 = esrc[j + 1];
        int s2 = esrc[j + 2];
        int s3 = esrc[j + 3];
        float as0 = a_src[(size_t)s0 * HEADS + h];
        float as1 = a_src[(size_t)s1 * HEADS + h];
        float as2 = a_src[(size_t)s2 * HEADS + h];
        float as3 = a_src[(size_t)s3 * HEADS + h];
        ushort4 v0 = *(const ushort4*)(h2 + (size_t)s0 * 256 + lane * 4);
        ushort4 v1 = *(const ushort4*)(h2 + (size_t)s1 * 256 + lane * 4);
        ushort4 v2 = *(const ushort4*)(h2 + (size_t)s2 * 256 + lane * 4);
        ushort4 v3 = *(const ushort4*)(h2 + (size_t)s3 * 256 + lane * 4);
        float e0 = as0 + ad; e0 = e0 > 0.f ? e0 : NEG_SLOPE * e0;
        float e1 = as1 + ad; e1 = e1 > 0.f ? e1 : NEG_SLOPE * e1;
        float e2 = as2 + ad; e2 = e2 > 0.f ? e2 : NEG_SLOPE * e2;
        float e3 = as3 + ad; e3 = e3 > 0.f ? e3 : NEG_SLOPE * e3;
        float p0 = __expf(e0);
        float p1 = __expf(e1);
        float p2 = __expf(e2);
        float p3 = __expf(e3);
        l += (p0 + p1) + (p2 + p3);
        acc0 = fmaf(p0, bf2f(v0.x), acc0);
        acc1 = fmaf(p0, bf2f(v0.y), acc1);
        acc2 = fmaf(p0, bf2f(v0.z), acc2);
        acc3 = fmaf(p0, bf2f(v0.w), acc3);
        acc0 = fmaf(p1, bf2f(v1.x), acc0);
        acc1 = fmaf(p1, bf2f(v1.y), acc1);
        acc2 = fmaf(p1, bf2f(v1.z), acc2);
        acc3 = fmaf(p1, bf2f(v1.w), acc3);
        acc0 = fmaf(p2, bf2f(v2.x), acc0);
        acc1 = fmaf(p2, bf2f(v2.y), acc1);
        acc2 = fmaf(p2, bf2f(v2.z), acc2);
        acc3 = fmaf(p2, bf2f(v2.w), acc3);
        acc0 = fmaf(p3, bf2f(v3.x), acc0);
        acc1 = fmaf(p3, bf2f(v3.y), acc1);
        acc2 = fmaf(p3, bf2f(v3.z), acc2);
        acc3 = fmaf(p3, bf2f(v3.w), acc3);
    }
    for (; j < end; ++j) {
        int s0 = esrc[j];
        float as0 = a_src[(size_t)s0 * HEADS + h];
        ushort4 v0 = *(const ushort4*)(h2 + (size_t)s0 * 256 + lane * 4);
        float e0 = as0 + ad; e0 = e0 > 0.f ? e0 : NEG_SLOPE * e0;
        float p0 = __expf(e0);
        l += p0;
        acc0 = fmaf(p0, bf2f(v0.x), acc0);
        acc1 = fmaf(p0, bf2f(v0.y), acc1);
        acc2 = fmaf(p0, bf2f(v0.z), acc2);
        acc3 = fmaf(p0, bf2f(v0.w), acc3);
    }

    float inv = 1.f / (l + 1e-16f);
    float r0 = acc0 * inv, r1 = acc1 * inv, r2 = acc2 * inv, r3 = acc3 * inv;

    // sum the 4 heads: lanes {cg, 16+cg, 32+cg, 48+cg}
    r0 += __shfl_xor(r0, 16, 64); r0 += __shfl_xor(r0, 32, 64);
    r1 += __shfl_xor(r1, 16, 64); r1 += __shfl_xor(r1, 32, 64);
    r2 += __shfl_xor(r2, 16, 64); r2 += __shfl_xor(r2, 32, 64);
    r3 += __shfl_xor(r3, 16, 64); r3 += __shfl_xor(r3, 32, 64);

    if (lane < 16) {
        float4 b4 = *(const float4*)(bias + cg * 4);
        float4 o;
        o.x = 0.25f * r0 + b4.x;
        o.y = 0.25f * r1 + b4.y;
        o.z = 0.25f * r2 + b4.z;
        o.w = 0.25f * r3 + b4.w;
        *(float4*)(out + (size_t)i * OUTC + cg * 4) = o;
    }
}

extern "C" void kernel_launch(void* const* d_in, const int* in_sizes, int n_in,
                              void* d_out, int out_size, void* d_ws, size_t ws_size,
                              hipStream_t stream)
{
    (void)n_in; (void)out_size; (void)ws_size;
    const float* x       = (const float*)d_in[0];
    const int*   edge    = (const int*)d_in[1];
    const float* W       = (const float*)d_in[2];
    const float* att_src = (const float*)d_in[3];
    const float* att_dst = (const float*)d_in[4];
    const float* bias    = (const float*)d_in[5];
    float* out = (float*)d_out;

    const int N = in_sizes[0] / INC;
    const int E = in_sizes[1] / 2;
    const int* srcA = edge;
    const int* dstA = edge + E;

    char* ws = (char*)d_ws;
    unsigned short* h2 = (unsigned short*)ws; ws += (size_t)N * (HEADS * OUTC) * sizeof(unsigned short);
    unsigned short* Wt = (unsigned short*)ws; ws += (size_t)256 * 256 * sizeof(unsigned short);
    float* a_src  = (float*)ws; ws += (size_t)N * HEADS * sizeof(float);
    float* a_dst  = (float*)ws; ws += (size_t)N * HEADS * sizeof(float);
    int* counts   = (int*)ws;   ws += (size_t)N * sizeof(int);
    int* offsets  = (int*)ws;   ws += (size_t)(N + 1) * sizeof(int) + 12;
    int* cursor   = (int*)ws;   ws += (size_t)N * sizeof(int);
    int* local    = (int*)ws;   ws += (size_t)N * sizeof(int);
    int* bsums    = (int*)ws;   ws += (size_t)1024 * sizeof(int);
    int* esrc     = (int*)ws;   ws += (size_t)E * sizeof(int);

    const int nb = (N + 255) / 256;

    wt_zero_kernel<<<256, 256, 0, stream>>>(W, Wt, counts, N);

    hist_kernel<<<(E + 255) / 256, 256, 0, stream>>>(dstA, counts, E);

    gemm_mfma<<<(N + 63) / 64, 256, 0, stream>>>(x, Wt, h2, N);

    att2_kernel<<<(N + 3) / 4, 256, 0, stream>>>(h2, att_src, att_dst, a_src, a_dst, N);

    scan1_kernel<<<nb, 256, 0, stream>>>(counts, local, bsums, N);
    scan3b_kernel<<<nb, 256, 0, stream>>>(local, bsums, offsets, cursor, N, E);
    scatter_kernel<<<(E + 255) / 256, 256, 0, stream>>>(srcA, dstA, cursor, esrc, E);

    fused_agg_kernel<<<(N + 3) / 4, 256, 0, stream>>>(h2, a_src, a_dst, offsets, esrc, bias, out, N);
}